// Round 1
// baseline (941.010 us; speedup 1.0000x reference)
//
#include <hip/hip_runtime.h>

#define NN 50000
#define NE 800000
#define HD 128
#define FBD 16
#define BN_EPS 1e-5f

// ---------------- zero scratch ----------------
__global__ __launch_bounds__(256) void zero_k(float* __restrict__ ws, long accN,
                                              long smallOff, int smallN) {
    long idx = (long)blockIdx.x * 256 + threadIdx.x;
    long stride = (long)gridDim.x * 256;
    float4* p = (float4*)ws;
    long n4 = accN / 4;
    for (long i = idx; i < n4; i += stride) p[i] = float4{0.f, 0.f, 0.f, 0.f};
    if (blockIdx.x == 0)
        for (int i = threadIdx.x; i < smallN; i += 256) ws[smallOff + i] = 0.f;
}

// ---------------- f32 tiled GEMM: out[M,128] = A[M,128] @ B[128,128] ----------------
// MODE 0: plain store.  MODE 1: v = relu(dot + dvec[j] + extra[i][j])
template <int MODE>
__global__ __launch_bounds__(256) void gemm_k(const float* __restrict__ A,
                                              const float* __restrict__ B,
                                              const float* __restrict__ extra,
                                              const float* __restrict__ dvec,
                                              float* __restrict__ out, int M) {
    __shared__ float Asm[32][66];   // [kk][row], stride 66 -> 2-way bank alias (free)
    __shared__ float Bsm[32][128];  // [kk][col]
    const int tid = threadIdx.x;
    const int tx = tid & 31;   // col group (4 cols)
    const int ty = tid >> 5;   // row group (8 rows)
    const int row0 = blockIdx.x * 64;
    const int rbase = ty * 8;
    const int cbase = tx * 4;
    float acc[8][4] = {};

    float4 dreg = {0.f, 0.f, 0.f, 0.f};
    if (MODE == 1) dreg = *(const float4*)&dvec[cbase];

    const int ak = tid & 31;
    const int ar = tid >> 5;
    for (int k0 = 0; k0 < HD; k0 += 32) {
#pragma unroll
        for (int i = 0; i < 8; ++i) {
            int r = ar + 8 * i;
            int gr = row0 + r;
            Asm[ak][r] = (gr < M) ? A[(long)gr * HD + k0 + ak] : 0.f;
        }
#pragma unroll
        for (int i = 0; i < 16; ++i) {
            int idx = tid + 256 * i;
            Bsm[idx >> 7][idx & 127] = B[(long)(k0 + (idx >> 7)) * HD + (idx & 127)];
        }
        __syncthreads();
#pragma unroll
        for (int kk = 0; kk < 32; ++kk) {
            float a[8], b[4];
            *(float2*)&a[0] = *(const float2*)&Asm[kk][rbase + 0];
            *(float2*)&a[2] = *(const float2*)&Asm[kk][rbase + 2];
            *(float2*)&a[4] = *(const float2*)&Asm[kk][rbase + 4];
            *(float2*)&a[6] = *(const float2*)&Asm[kk][rbase + 6];
            *(float4*)&b[0] = *(const float4*)&Bsm[kk][cbase];
#pragma unroll
            for (int r = 0; r < 8; ++r)
#pragma unroll
                for (int c = 0; c < 4; ++c) acc[r][c] = fmaf(a[r], b[c], acc[r][c]);
        }
        __syncthreads();
    }
#pragma unroll
    for (int r = 0; r < 8; ++r) {
        int gr = row0 + rbase + r;
        if (gr < M) {
            float4 v = {acc[r][0], acc[r][1], acc[r][2], acc[r][3]};
            if (MODE == 1) {
                float4 f = *(const float4*)&extra[(long)gr * HD + cbase];
                v.x = fmaxf(v.x + dreg.x + f.x, 0.f);
                v.y = fmaxf(v.y + dreg.y + f.y, 0.f);
                v.z = fmaxf(v.z + dreg.z + f.z, 0.f);
                v.w = fmaxf(v.w + dreg.w + f.w, 0.f);
            }
            *(float4*)&out[(long)gr * HD + cbase] = v;
        }
    }
}

// ---------------- edge gather+project+scatter ----------------
// per edge e: m = Z[src[e]] + edge_w[e] @ bond_W + bond_b ; acc[dst[e]] += m (atomic)
__global__ __launch_bounds__(256) void edge_k(const float* __restrict__ edge_w,
                                              const int* __restrict__ src,
                                              const int* __restrict__ dst,
                                              const float* __restrict__ bond_W,
                                              const float* __restrict__ bond_b,
                                              const float* __restrict__ Z,
                                              float* __restrict__ acc) {
    __shared__ float bW[FBD * HD];
    __shared__ float bb[HD];
    int tid = threadIdx.x;
    for (int i = tid; i < FBD * HD; i += 256) bW[i] = bond_W[i];
    if (tid < HD) bb[tid] = bond_b[tid];
    __syncthreads();
    const int lane = tid & 63;
    const int gw = blockIdx.x * 4 + (tid >> 6);
    const int nw = gridDim.x * 4;
    const int c0 = lane * 2;
    for (int e = gw; e < NE; e += nw) {
        int s = src[e];
        int dt = dst[e];
        const float4* ew4 = (const float4*)(edge_w + (long)e * FBD);
        float4 w0 = ew4[0], w1 = ew4[1], w2 = ew4[2], w3 = ew4[3];
        float ew[16] = {w0.x, w0.y, w0.z, w0.w, w1.x, w1.y, w1.z, w1.w,
                        w2.x, w2.y, w2.z, w2.w, w3.x, w3.y, w3.z, w3.w};
        float m0 = bb[c0], m1 = bb[c0 + 1];
#pragma unroll
        for (int k = 0; k < FBD; ++k) {
            float2 w = *(const float2*)&bW[k * HD + c0];
            m0 = fmaf(ew[k], w.x, m0);
            m1 = fmaf(ew[k], w.y, m1);
        }
        float2 z = *(const float2*)&Z[(long)s * HD + c0];
        m0 += z.x;
        m1 += z.y;
        float* ap = &acc[(long)dt * HD + c0];
        unsafeAtomicAdd(ap, m0);
        unsafeAtomicAdd(ap + 1, m1);
    }
}

// ---------------- column stats (sum, sumsq); MODE1 also does relu(v+bias) writeback ----------------
template <int MODE>
__global__ __launch_bounds__(256) void stats_k(float* __restrict__ X,
                                               const float* __restrict__ bias,
                                               float* __restrict__ stats, int M) {
    int tid = threadIdx.x;
    int col = tid & (HD - 1);
    int half = tid >> 7;
    int row0 = blockIdx.x * 128;
    int rmax = min(128, M - row0);
    float b = (MODE == 1) ? bias[col] : 0.f;
    float s = 0.f, s2 = 0.f;
    for (int r = half; r < rmax; r += 2) {
        long idx = (long)(row0 + r) * HD + col;
        float v = X[idx];
        if (MODE == 1) {
            v = fmaxf(v + b, 0.f);
            X[idx] = v;
        }
        s += v;
        s2 += v * v;
    }
    __shared__ float red[256];
    red[tid] = s;
    __syncthreads();
    if (half == 0) unsafeAtomicAdd(&stats[col], s + red[tid + 128]);
    __syncthreads();
    red[tid] = s2;
    __syncthreads();
    if (half == 0) unsafeAtomicAdd(&stats[HD + col], s2 + red[tid + 128]);
}

// ---------------- finalize BN1 -> per-column affine (a1, c1) ----------------
__global__ void fin1_k(const float* __restrict__ stats, const float* __restrict__ gamma,
                       const float* __restrict__ beta, float* __restrict__ a1,
                       float* __restrict__ c1) {
    int c = threadIdx.x;
    float mean = stats[c] * (1.0f / NN);
    float var = stats[HD + c] * (1.0f / NN) - mean * mean;
    float inv = rsqrtf(var + BN_EPS);
    float g = gamma[c];
    a1[c] = g * inv;
    c1[c] = beta[c] - mean * inv * g;
}

// ---------------- fold BN1 affine into W2: W2p = a1 (.) W2 ; d = c1 @ W2 + b2 ----------------
__global__ void prep2_k(const float* __restrict__ W2, const float* __restrict__ b2,
                        const float* __restrict__ a1, const float* __restrict__ c1,
                        float* __restrict__ W2p, float* __restrict__ dv) {
    int j = threadIdx.x;  // 128 threads
    float dj = b2[j];
    for (int k = 0; k < HD; ++k) {
        float w = W2[k * HD + j];
        W2p[k * HD + j] = a1[k] * w;
        dj = fmaf(c1[k], w, dj);
    }
    dv[j] = dj;
}

// ---------------- final: out = Z * a2[col] + c2[col] (BN2 folded, in-place safe) ----------------
__global__ __launch_bounds__(256) void out_k(const float* __restrict__ Z,
                                             const float* __restrict__ stats2,
                                             const float* __restrict__ gamma2,
                                             const float* __restrict__ beta2,
                                             float* __restrict__ out, int M) {
    int tid = threadIdx.x;
    int col = tid & (HD - 1);
    int half = tid >> 7;
    float mean = stats2[col] * (1.0f / NN);
    float var = stats2[HD + col] * (1.0f / NN) - mean * mean;
    float inv = rsqrtf(var + BN_EPS);
    float g = gamma2[col];
    float a = g * inv;
    float c = beta2[col] - mean * inv * g;
    int row0 = blockIdx.x * 128;
    int rmax = min(128, M - row0);
    for (int r = half; r < rmax; r += 2) {
        long idx = (long)(row0 + r) * HD + col;
        out[idx] = fmaf(Z[idx], a, c);
    }
}

extern "C" void kernel_launch(void* const* d_in, const int* in_sizes, int n_in,
                              void* d_out, int out_size, void* d_ws, size_t ws_size,
                              hipStream_t stream) {
    const float* features = (const float*)d_in[0];
    const float* edge_w = (const float*)d_in[1];
    const int* src = (const int*)d_in[2];
    const int* dst = (const int*)d_in[3];
    const float* bond_W = (const float*)d_in[4];
    const float* bond_b = (const float*)d_in[5];
    const float* W1 = (const float*)d_in[6];
    const float* b1 = (const float*)d_in[7];
    const float* W2 = (const float*)d_in[8];
    const float* b2 = (const float*)d_in[9];
    const float* gamma1 = (const float*)d_in[10];
    const float* beta1 = (const float*)d_in[11];
    const float* gamma2 = (const float*)d_in[12];
    const float* beta2 = (const float*)d_in[13];
    float* out = (float*)d_out;
    float* ws = (float*)d_ws;

    const long NH = (long)NN * HD;
    float* acc = ws;               // [N,H]
    float* W2p = ws + NH;          // [H,H]
    float* dv = W2p + HD * HD;     // [H]
    float* s1 = dv + HD;           // [2H]
    float* s2 = s1 + 2 * HD;       // [2H]
    float* a1 = s2 + 2 * HD;       // [H]
    float* c1 = a1 + HD;           // [H]
    float* Z = out;                // reuse d_out as scratch (lifetimes disjoint)

    // zero acc + stats (ws is poisoned 0xAA before every call)
    zero_k<<<1024, 256, 0, stream>>>(ws, NH, (long)(s1 - ws), 4 * HD);
    // Z = features @ W1
    gemm_k<0><<<(NN + 63) / 64, 256, 0, stream>>>(features, W1, nullptr, nullptr, Z, NN);
    // acc[dst] += Z[src] + edge_w @ bond_W + bond_b
    edge_k<<<6250, 256, 0, stream>>>(edge_w, src, dst, bond_W, bond_b, Z, acc);
    // acc = relu(acc + b1); s1 = column {sum, sumsq}
    stats_k<1><<<(NN + 127) / 128, 256, 0, stream>>>(acc, b1, s1, NN);
    // BN1 -> affine (a1, c1)
    fin1_k<<<1, HD, 0, stream>>>(s1, gamma1, beta1, a1, c1);
    // fold BN1 into W2
    prep2_k<<<1, HD, 0, stream>>>(W2, b2, a1, c1, W2p, dv);
    // Z = relu(acc @ W2p + dv + features)
    gemm_k<1><<<(NN + 63) / 64, 256, 0, stream>>>(acc, W2p, features, dv, Z, NN);
    // s2 = column stats of Z
    stats_k<0><<<(NN + 127) / 128, 256, 0, stream>>>(Z, nullptr, s2, NN);
    // out = Z * a2 + c2 (in place)
    out_k<<<(NN + 127) / 128, 256, 0, stream>>>(Z, s2, gamma2, beta2, out, NN);
}

// Round 2
// 646.885 us; speedup vs baseline: 1.4547x; 1.4547x over previous
//
#include <hip/hip_runtime.h>

#define NN 50000
#define NE 800000
#define HD 128
#define FBD 16
#define BN_EPS 1e-5f

// ---------------- zero cnt + stats ----------------
__global__ __launch_bounds__(256) void zero2_k(int* __restrict__ cnt,
                                               float* __restrict__ st, int nst) {
    int i = blockIdx.x * 256 + threadIdx.x;
    if (i < NN) cnt[i] = 0;
    if (i < nst) st[i] = 0.f;
}

// ---------------- degree histogram ----------------
__global__ __launch_bounds__(256) void hist_k(const int* __restrict__ dst,
                                              int* __restrict__ cnt) {
    int e = blockIdx.x * 256 + threadIdx.x;
    if (e < NE) atomicAdd(&cnt[dst[e]], 1);
}

// ---------------- single-block exclusive scan -> rowptr, wpos ----------------
__global__ __launch_bounds__(1024) void scan_k(const int* __restrict__ cnt,
                                               int* __restrict__ rowptr,
                                               int* __restrict__ wpos) {
    __shared__ int part[1024];
    int t = threadIdx.x;
    const int CH = (NN + 1023) / 1024;  // 49
    int lo = t * CH, hi = min(lo + CH, NN);
    int s = 0;
    for (int i = lo; i < hi; ++i) s += cnt[i];
    part[t] = s;
    __syncthreads();
    for (int off = 1; off < 1024; off <<= 1) {
        int v = (t >= off) ? part[t - off] : 0;
        __syncthreads();
        part[t] += v;
        __syncthreads();
    }
    int run = (t == 0) ? 0 : part[t - 1];
    for (int i = lo; i < hi; ++i) {
        rowptr[i] = run;
        wpos[i] = run;
        run += cnt[i];
    }
    if (t == 1023) rowptr[NN] = part[1023];
}

// ---------------- scatter edge ids into CSR ----------------
__global__ __launch_bounds__(256) void scat_k(const int* __restrict__ dst,
                                              int* __restrict__ wpos,
                                              int* __restrict__ eidx) {
    int e = blockIdx.x * 256 + threadIdx.x;
    if (e < NE) {
        int p = atomicAdd(&wpos[dst[e]], 1);
        eidx[p] = e;
    }
}

// ---------------- gather: S[n] = sum features[src], T[n] = sum edge_w ----------------
__global__ __launch_bounds__(256) void gather_k(const int* __restrict__ rowptr,
                                                const int* __restrict__ eidx,
                                                const int* __restrict__ src,
                                                const float* __restrict__ features,
                                                const float* __restrict__ edge_w,
                                                float* __restrict__ S,
                                                float* __restrict__ T) {
    int wid = blockIdx.x * 4 + (threadIdx.x >> 6);
    if (wid >= NN) return;
    int lane = threadIdx.x & 63;
    int base = rowptr[wid], end = rowptr[wid + 1];
    float2 acc = {0.f, 0.f};
    float tacc = 0.f;
    for (int b = base; b < end; b += 64) {
        int n = min(64, end - b);
        int myE = (lane < n) ? eidx[b + lane] : 0;
        int myS = (lane < n) ? src[myE] : 0;
        for (int i = 0; i < n; ++i) {
            int e = __shfl(myE, i);
            int s = __shfl(myS, i);
            float2 f = *(const float2*)&features[(long)s * HD + lane * 2];
            acc.x += f.x;
            acc.y += f.y;
            if (lane < FBD) tacc += edge_w[(long)e * FBD + lane];
        }
    }
    *(float2*)&S[(long)wid * HD + lane * 2] = acc;
    if (lane < FBD) T[(long)wid * FBD + lane] = tacc;
}

// ---------------- f32 tiled GEMM: out[M,128] = A[M,128] @ B[128,128] + extras ----------------
// MODE 1: v = relu(dot + dvec[j] + extra[i][j]); fused col stats -> stats
// MODE 2: v = relu(dot + T@bondW + deg*bondb + dvec[j]); fused col stats (dvec=b1)
template <int MODE>
__global__ __launch_bounds__(256) void gemm_k(const float* __restrict__ A,
                                              const float* __restrict__ B,
                                              const float* __restrict__ extra,
                                              const float* __restrict__ dvec,
                                              float* __restrict__ out, int M,
                                              const float* __restrict__ T,
                                              const float* __restrict__ bondW,
                                              const int* __restrict__ cnt,
                                              const float* __restrict__ bondb,
                                              float* __restrict__ stats) {
    __shared__ float Asm[32][66];
    __shared__ float Bsm[32][128];
    __shared__ float4 redS[8][32];
    __shared__ float4 redQ[8][32];
    const int tid = threadIdx.x;
    const int tx = tid & 31;
    const int ty = tid >> 5;
    const int row0 = blockIdx.x * 64;
    const int rbase = ty * 8;
    const int cbase = tx * 4;
    float acc[8][4] = {};

    float4 dreg = *(const float4*)&dvec[cbase];

    const int ak = tid & 31;
    const int ar = tid >> 5;
    for (int k0 = 0; k0 < HD; k0 += 32) {
#pragma unroll
        for (int i = 0; i < 8; ++i) {
            int r = ar + 8 * i;
            int gr = row0 + r;
            Asm[ak][r] = (gr < M) ? A[(long)gr * HD + k0 + ak] : 0.f;
        }
#pragma unroll
        for (int i = 0; i < 16; ++i) {
            int idx = tid + 256 * i;
            Bsm[idx >> 7][idx & 127] = B[(long)(k0 + (idx >> 7)) * HD + (idx & 127)];
        }
        __syncthreads();
#pragma unroll
        for (int kk = 0; kk < 32; ++kk) {
            float a[8], b[4];
            *(float2*)&a[0] = *(const float2*)&Asm[kk][rbase + 0];
            *(float2*)&a[2] = *(const float2*)&Asm[kk][rbase + 2];
            *(float2*)&a[4] = *(const float2*)&Asm[kk][rbase + 4];
            *(float2*)&a[6] = *(const float2*)&Asm[kk][rbase + 6];
            *(float4*)&b[0] = *(const float4*)&Bsm[kk][cbase];
#pragma unroll
            for (int r = 0; r < 8; ++r)
#pragma unroll
                for (int c = 0; c < 4; ++c) acc[r][c] = fmaf(a[r], b[c], acc[r][c]);
        }
        __syncthreads();
    }

    if (MODE == 2) {
        __shared__ float Tsm[64][17];
        __shared__ float Bbs[16][128];
        __shared__ float degs[64];
        for (int i = tid; i < 64 * FBD; i += 256) {
            int r = i >> 4, k = i & 15;
            int gr = row0 + r;
            Tsm[r][k] = (gr < M) ? T[(long)gr * FBD + k] : 0.f;
        }
        for (int i = tid; i < FBD * HD; i += 256) Bbs[i >> 7][i & 127] = bondW[i];
        if (tid < 64) {
            int gr = row0 + tid;
            degs[tid] = (gr < M) ? (float)cnt[gr] : 0.f;
        }
        __syncthreads();
        float4 bb = *(const float4*)&bondb[cbase];
#pragma unroll
        for (int k = 0; k < FBD; ++k) {
            float4 b4 = *(const float4*)&Bbs[k][cbase];
#pragma unroll
            for (int r = 0; r < 8; ++r) {
                float a = Tsm[rbase + r][k];
                acc[r][0] = fmaf(a, b4.x, acc[r][0]);
                acc[r][1] = fmaf(a, b4.y, acc[r][1]);
                acc[r][2] = fmaf(a, b4.z, acc[r][2]);
                acc[r][3] = fmaf(a, b4.w, acc[r][3]);
            }
        }
#pragma unroll
        for (int r = 0; r < 8; ++r) {
            float dg = degs[rbase + r];
            acc[r][0] = fmaf(dg, bb.x, acc[r][0]);
            acc[r][1] = fmaf(dg, bb.y, acc[r][1]);
            acc[r][2] = fmaf(dg, bb.z, acc[r][2]);
            acc[r][3] = fmaf(dg, bb.w, acc[r][3]);
        }
    }

    // epilogue: bias/extra + relu + store + partial column stats
    float4 ps = {0.f, 0.f, 0.f, 0.f}, pq = {0.f, 0.f, 0.f, 0.f};
#pragma unroll
    for (int r = 0; r < 8; ++r) {
        int gr = row0 + rbase + r;
        if (gr < M) {
            float4 v = {acc[r][0] + dreg.x, acc[r][1] + dreg.y, acc[r][2] + dreg.z,
                        acc[r][3] + dreg.w};
            if (MODE == 1) {
                float4 f = *(const float4*)&extra[(long)gr * HD + cbase];
                v.x += f.x; v.y += f.y; v.z += f.z; v.w += f.w;
            }
            v.x = fmaxf(v.x, 0.f);
            v.y = fmaxf(v.y, 0.f);
            v.z = fmaxf(v.z, 0.f);
            v.w = fmaxf(v.w, 0.f);
            *(float4*)&out[(long)gr * HD + cbase] = v;
            ps.x += v.x; ps.y += v.y; ps.z += v.z; ps.w += v.w;
            pq.x += v.x * v.x; pq.y += v.y * v.y; pq.z += v.z * v.z; pq.w += v.w * v.w;
        }
    }
    redS[ty][tx] = ps;
    redQ[ty][tx] = pq;
    __syncthreads();
    if (ty == 0) {
        float4 s = redS[0][tx], q = redQ[0][tx];
#pragma unroll
        for (int r = 1; r < 8; ++r) {
            float4 s2 = redS[r][tx], q2 = redQ[r][tx];
            s.x += s2.x; s.y += s2.y; s.z += s2.z; s.w += s2.w;
            q.x += q2.x; q.y += q2.y; q.z += q2.z; q.w += q2.w;
        }
        unsafeAtomicAdd(&stats[cbase + 0], s.x);
        unsafeAtomicAdd(&stats[cbase + 1], s.y);
        unsafeAtomicAdd(&stats[cbase + 2], s.z);
        unsafeAtomicAdd(&stats[cbase + 3], s.w);
        unsafeAtomicAdd(&stats[HD + cbase + 0], q.x);
        unsafeAtomicAdd(&stats[HD + cbase + 1], q.y);
        unsafeAtomicAdd(&stats[HD + cbase + 2], q.z);
        unsafeAtomicAdd(&stats[HD + cbase + 3], q.w);
    }
}

// ---------------- finalize BN1 -> per-column affine (a1, c1) ----------------
__global__ void fin1_k(const float* __restrict__ stats, const float* __restrict__ gamma,
                       const float* __restrict__ beta, float* __restrict__ a1,
                       float* __restrict__ c1) {
    int c = threadIdx.x;
    float mean = stats[c] * (1.0f / NN);
    float var = stats[HD + c] * (1.0f / NN) - mean * mean;
    float inv = rsqrtf(var + BN_EPS);
    float g = gamma[c];
    a1[c] = g * inv;
    c1[c] = beta[c] - mean * inv * g;
}

// ---------------- fold BN1 affine into W2 ----------------
__global__ void prep2_k(const float* __restrict__ W2, const float* __restrict__ b2,
                        const float* __restrict__ a1, const float* __restrict__ c1,
                        float* __restrict__ W2p, float* __restrict__ dv) {
    int j = threadIdx.x;  // 128 threads
    float dj = b2[j];
    for (int k = 0; k < HD; ++k) {
        float w = W2[k * HD + j];
        W2p[k * HD + j] = a1[k] * w;
        dj = fmaf(c1[k], w, dj);
    }
    dv[j] = dj;
}

// ---------------- final: out = Z * a2[col] + c2[col] ----------------
__global__ __launch_bounds__(256) void out_k(const float* __restrict__ Z,
                                             const float* __restrict__ stats2,
                                             const float* __restrict__ gamma2,
                                             const float* __restrict__ beta2,
                                             float* __restrict__ out, int M) {
    int tid = threadIdx.x;
    int col = tid & (HD - 1);
    int half = tid >> 7;
    float mean = stats2[col] * (1.0f / NN);
    float var = stats2[HD + col] * (1.0f / NN) - mean * mean;
    float inv = rsqrtf(var + BN_EPS);
    float g = gamma2[col];
    float a = g * inv;
    float c = beta2[col] - mean * inv * g;
    int row0 = blockIdx.x * 128;
    int rmax = min(128, M - row0);
    for (int r = half; r < rmax; r += 2) {
        long idx = (long)(row0 + r) * HD + col;
        out[idx] = fmaf(Z[idx], a, c);
    }
}

extern "C" void kernel_launch(void* const* d_in, const int* in_sizes, int n_in,
                              void* d_out, int out_size, void* d_ws, size_t ws_size,
                              hipStream_t stream) {
    const float* features = (const float*)d_in[0];
    const float* edge_w = (const float*)d_in[1];
    const int* src = (const int*)d_in[2];
    const int* dst = (const int*)d_in[3];
    const float* bond_W = (const float*)d_in[4];
    const float* bond_b = (const float*)d_in[5];
    const float* W1 = (const float*)d_in[6];
    const float* b1 = (const float*)d_in[7];
    const float* W2 = (const float*)d_in[8];
    const float* b2 = (const float*)d_in[9];
    const float* gamma1 = (const float*)d_in[10];
    const float* beta1 = (const float*)d_in[11];
    const float* gamma2 = (const float*)d_in[12];
    const float* beta2 = (const float*)d_in[13];
    float* out = (float*)d_out;
    float* ws = (float*)d_ws;

    const long NH = (long)NN * HD;
    float* S = ws;                       // [N,128] -> becomes X1 in-place
    float* T = S + NH;                   // [N,16]
    int* cnt = (int*)(T + (long)NN * FBD);
    int* rowptr = cnt + NN;              // [N+1]
    int* wpos = rowptr + NN + 1;         // [N]
    int* eidx = wpos + NN;               // [E]
    float* W2p = (float*)(eidx + NE);    // [128,128]
    float* dv = W2p + HD * HD;           // [128]
    float* s1 = dv + HD;                 // [256]
    float* s2 = s1 + 2 * HD;             // [256]
    float* a1 = s2 + 2 * HD;             // [128]
    float* c1 = a1 + HD;                 // [128]

    zero2_k<<<(NN + 255) / 256, 256, 0, stream>>>(cnt, s1, 4 * HD);
    hist_k<<<(NE + 255) / 256, 256, 0, stream>>>(dst, cnt);
    scan_k<<<1, 1024, 0, stream>>>(cnt, rowptr, wpos);
    scat_k<<<(NE + 255) / 256, 256, 0, stream>>>(dst, wpos, eidx);
    gather_k<<<(NN + 3) / 4, 256, 0, stream>>>(rowptr, eidx, src, features, edge_w, S, T);
    // X1 = relu(S@W1 + T@bond_W + deg*bond_b + b1), stats -> s1 (in-place on S)
    gemm_k<2><<<(NN + 63) / 64, 256, 0, stream>>>(S, W1, nullptr, b1, S, NN, T, bond_W,
                                                  cnt, bond_b, s1);
    fin1_k<<<1, HD, 0, stream>>>(s1, gamma1, beta1, a1, c1);
    prep2_k<<<1, HD, 0, stream>>>(W2, b2, a1, c1, W2p, dv);
    // Z = relu(X1@W2p + dv + features), stats -> s2
    gemm_k<1><<<(NN + 63) / 64, 256, 0, stream>>>(S, W2p, features, dv, out, NN, nullptr,
                                                  nullptr, nullptr, nullptr, s2);
    out_k<<<(NN + 127) / 128, 256, 0, stream>>>(out, s2, gamma2, beta2, out, NN);
}

// Round 3
// 483.450 us; speedup vs baseline: 1.9464x; 1.3381x over previous
//
#include <hip/hip_runtime.h>

#define NN 50000
#define NE 800000
#define HD 128
#define FBD 16
#define BN_EPS 1e-5f

typedef __attribute__((ext_vector_type(8))) short short8;
typedef __attribute__((ext_vector_type(4))) float f32x4;

__device__ __forceinline__ short f2bf(float x) {
    unsigned int u = __float_as_uint(x);
    u += 0x7fff + ((u >> 16) & 1);   // RNE
    return (short)(u >> 16);
}

// ---------------- prep0: zero cnt + stats, build Bt1g = [W1;bondW;bondb;b1;0]^T bf16 ----------------
__global__ __launch_bounds__(256) void prep0_k(const float* __restrict__ W1,
                                               const float* __restrict__ bond_W,
                                               const float* __restrict__ bond_b,
                                               const float* __restrict__ b1,
                                               int* __restrict__ cnt,
                                               float* __restrict__ stats,
                                               unsigned short* __restrict__ Bt1g) {
    int i = blockIdx.x * 256 + threadIdx.x;
    if (i < NN) cnt[i] = 0;
    if (i < 512) stats[i] = 0.f;  // s1[256] + s2[256]
    if (i < 128 * 160) {
        int c = i / 160, k = i % 160;
        float v;
        if (k < 128) v = W1[k * HD + c];
        else if (k < 144) v = bond_W[(k - 128) * HD + c];
        else if (k == 144) v = bond_b[c];
        else if (k == 145) v = b1[c];
        else v = 0.f;
        Bt1g[i] = (unsigned short)f2bf(v);
    }
}

// ---------------- degree histogram ----------------
__global__ __launch_bounds__(256) void hist_k(const int* __restrict__ dst,
                                              int* __restrict__ cnt) {
    int e = blockIdx.x * 256 + threadIdx.x;
    if (e < NE) atomicAdd(&cnt[e < NE ? dst[e] : 0], 1);
}

// ---------------- single-block exclusive scan -> rowptr, wpos ----------------
__global__ __launch_bounds__(1024) void scan_k(const int* __restrict__ cnt,
                                               int* __restrict__ rowptr,
                                               int* __restrict__ wpos) {
    __shared__ int part[1024];
    int t = threadIdx.x;
    const int CH = (NN + 1023) / 1024;  // 49
    int lo = t * CH, hi = min(lo + CH, NN);
    int s = 0;
    for (int i = lo; i < hi; ++i) s += cnt[i];
    part[t] = s;
    __syncthreads();
    for (int off = 1; off < 1024; off <<= 1) {
        int v = (t >= off) ? part[t - off] : 0;
        __syncthreads();
        part[t] += v;
        __syncthreads();
    }
    int run = (t == 0) ? 0 : part[t - 1];
    for (int i = lo; i < hi; ++i) {
        rowptr[i] = run;
        wpos[i] = run;
        run += cnt[i];
    }
    if (t == 1023) rowptr[NN] = part[1023];
}

// ---------------- scatter edge ids into CSR ----------------
__global__ __launch_bounds__(256) void scat_k(const int* __restrict__ dst,
                                              int* __restrict__ wpos,
                                              int* __restrict__ eidx) {
    int e = blockIdx.x * 256 + threadIdx.x;
    if (e < NE) {
        int p = atomicAdd(&wpos[dst[e]], 1);
        eidx[p] = e;
    }
}

// ---------------- gather: S[n] = sum features[src], TD[n] = [sum edge_w | deg | 1 | 0..] ----------------
__global__ __launch_bounds__(256) void gather_k(const int* __restrict__ rowptr,
                                                const int* __restrict__ eidx,
                                                const int* __restrict__ src,
                                                const float* __restrict__ features,
                                                const float* __restrict__ edge_w,
                                                float* __restrict__ S,
                                                float* __restrict__ TD) {
    int wid = blockIdx.x * 4 + (threadIdx.x >> 6);
    if (wid >= NN) return;
    const int lane = threadIdx.x & 63;
    const int g = lane >> 4, cc = lane & 15;
    int base = rowptr[wid], end = rowptr[wid + 1];
    float2 acc = {0.f, 0.f};
    float tacc = 0.f;
    for (int b = base; b < end; b += 64) {
        int n = min(64, end - b);
        int myE = eidx[b + min(lane, n - 1)];
        int myS = src[myE];
        int i = 0;
        for (; i + 4 <= n; i += 4) {
            int s0 = __shfl(myS, i), s1_ = __shfl(myS, i + 1);
            int s2_ = __shfl(myS, i + 2), s3_ = __shfl(myS, i + 3);
            int eg = __shfl(myE, i + g);
            float2 f0 = *(const float2*)&features[(long)s0 * HD + lane * 2];
            float2 f1 = *(const float2*)&features[(long)s1_ * HD + lane * 2];
            float2 f2 = *(const float2*)&features[(long)s2_ * HD + lane * 2];
            float2 f3 = *(const float2*)&features[(long)s3_ * HD + lane * 2];
            float w = edge_w[(long)eg * FBD + cc];
            acc.x += f0.x + f1.x + f2.x + f3.x;
            acc.y += f0.y + f1.y + f2.y + f3.y;
            tacc += w;
        }
        for (; i < n; ++i) {
            int s0 = __shfl(myS, i);
            int e0 = __shfl(myE, i);
            float2 f0 = *(const float2*)&features[(long)s0 * HD + lane * 2];
            acc.x += f0.x;
            acc.y += f0.y;
            if (g == 0) tacc += edge_w[(long)e0 * FBD + cc];
        }
    }
    *(float2*)&S[(long)wid * HD + lane * 2] = acc;
    tacc += __shfl_xor(tacc, 16);
    tacc += __shfl_xor(tacc, 32);
    if (lane < 32) {
        float v = (lane < 16) ? tacc
                              : (lane == 16 ? (float)(end - base) : (lane == 17 ? 1.f : 0.f));
        TD[(long)wid * 32 + lane] = v;
    }
}

// ---------------- bf16 MFMA GEMM: out[M,128] = relu(A[M,KB] @ Bt^T) (+dvec+extra), col stats ----------------
// MODE 1: K=160 (last k-step from TD; bias/bond folded into B). MODE 2: K=128, +dvec[col]+extra[row][col].
template <int MODE, int KB>
__global__ __launch_bounds__(256) void mfma_gemm_k(const float* __restrict__ A,
                                                   const float* __restrict__ TD,
                                                   const unsigned short* __restrict__ Btg,
                                                   const float* __restrict__ extra,
                                                   const float* __restrict__ dvec,
                                                   float* __restrict__ out,
                                                   float* __restrict__ stats, int M) {
    __shared__ unsigned short Bt[128 * KB];
    __shared__ float redS[4][128];
    __shared__ float redQ[4][128];
    const int tid = threadIdx.x;

    // stage B^T (bf16) global -> LDS with XOR swizzle ((c&7)<<4 on byte addr)
    const int nch = 128 * KB * 2 / 16;
    for (int id = tid; id < nch; id += 256) {
        int c = id / (KB / 8);
        int byte = id * 16;
        int sw = byte ^ ((c & 7) << 4);
        *(uint4*)((char*)Bt + sw) = *(const uint4*)((const char*)Btg + byte);
    }
    __syncthreads();

    const int l = tid & 63, wid = tid >> 6;
    const int row0 = blockIdx.x * 64 + wid * 16;
    const int cc = l & 15, g = l >> 4, ko = g * 8;
    const long arow = min(row0 + cc, M - 1);

    f32x4 acc[8] = {};

#pragma unroll
    for (int ks = 0; ks < KB / 32; ++ks) {
        const float* ap;
        if (MODE == 1 && ks == 4)
            ap = TD + arow * 32 + ko;
        else
            ap = A + arow * HD + ks * 32 + ko;
        float4 a0 = *(const float4*)ap;
        float4 a1 = *(const float4*)(ap + 4);
        short8 af;
        af[0] = f2bf(a0.x); af[1] = f2bf(a0.y); af[2] = f2bf(a0.z); af[3] = f2bf(a0.w);
        af[4] = f2bf(a1.x); af[5] = f2bf(a1.y); af[6] = f2bf(a1.z); af[7] = f2bf(a1.w);
#pragma unroll
        for (int cb = 0; cb < 8; ++cb) {
            int byte = (cb * 16 + cc) * (KB * 2) + (ks * 32 + ko) * 2;
            byte ^= (cc & 7) << 4;
            short8 bf = *(const short8*)((const char*)Bt + byte);
            acc[cb] = __builtin_amdgcn_mfma_f32_16x16x32_bf16(af, bf, acc[cb], 0, 0, 0);
        }
    }

    // epilogue: (+dvec+extra) relu, store, column stats
#pragma unroll
    for (int cb = 0; cb < 8; ++cb) {
        int col = cb * 16 + cc;
        float dva = (MODE == 2) ? dvec[col] : 0.f;
        float s = 0.f, q = 0.f;
#pragma unroll
        for (int r = 0; r < 4; ++r) {
            int grow = row0 + g * 4 + r;
            if (grow < M) {
                float v = acc[cb][r] + dva;
                if (MODE == 2) v += extra[(long)grow * HD + col];
                v = fmaxf(v, 0.f);
                out[(long)grow * HD + col] = v;
                s += v;
                q += v * v;
            }
        }
        s += __shfl_xor(s, 16);
        s += __shfl_xor(s, 32);
        q += __shfl_xor(q, 16);
        q += __shfl_xor(q, 32);
        if (l < 16) {
            redS[wid][col] = s;
            redQ[wid][col] = q;
        }
    }
    __syncthreads();
    if (tid < 128) {
        float s = redS[0][tid] + redS[1][tid] + redS[2][tid] + redS[3][tid];
        unsafeAtomicAdd(&stats[tid], s);
    } else {
        int c = tid - 128;
        float q = redQ[0][c] + redQ[1][c] + redQ[2][c] + redQ[3][c];
        unsafeAtomicAdd(&stats[128 + c], q);
    }
}

// ---------------- fin: BN1 affine from s1; build Bt2g = (a1 (.) W2)^T bf16 and dv = c1@W2 + b2 ----------------
__global__ __launch_bounds__(128) void fin_k(const float* __restrict__ stats,
                                             const float* __restrict__ gamma1,
                                             const float* __restrict__ beta1,
                                             const float* __restrict__ W2,
                                             const float* __restrict__ b2,
                                             unsigned short* __restrict__ Bt2g,
                                             float* __restrict__ dv) {
    __shared__ float sa[128], sc[128];
    int j = threadIdx.x;
    float mean = stats[j] * (1.f / NN);
    float var = stats[128 + j] * (1.f / NN) - mean * mean;
    float inv = rsqrtf(var + BN_EPS);
    float gg = gamma1[j];
    sa[j] = gg * inv;
    sc[j] = beta1[j] - mean * inv * gg;
    __syncthreads();
    float dj = b2[j];
    for (int k0 = 0; k0 < HD; k0 += 8) {
        short8 v;
#pragma unroll
        for (int u = 0; u < 8; ++u) {
            float w = W2[(k0 + u) * HD + j];
            v[u] = f2bf(sa[k0 + u] * w);
            dj = fmaf(sc[k0 + u], w, dj);
        }
        *(short8*)&Bt2g[(long)j * HD + k0] = v;
    }
    dv[j] = dj;
}

// ---------------- final: out = Z * a2[col] + c2[col] (BN2), float4 ----------------
__global__ __launch_bounds__(256) void out_k(const float* __restrict__ Z,
                                             const float* __restrict__ stats2,
                                             const float* __restrict__ gamma2,
                                             const float* __restrict__ beta2,
                                             float* __restrict__ out) {
    long i = (long)blockIdx.x * 256 + threadIdx.x;
    const long n4 = (long)NN * HD / 4;
    if (i >= n4) return;
    int col = (int)((i & 31) << 2);
    float4 z = ((const float4*)Z)[i];
    float4 o;
    float* zp = (float*)&z;
    float* op = (float*)&o;
#pragma unroll
    for (int c = 0; c < 4; ++c) {
        float mean = stats2[col + c] * (1.f / NN);
        float var = stats2[128 + col + c] * (1.f / NN) - mean * mean;
        float inv = rsqrtf(var + BN_EPS);
        float gg = gamma2[col + c];
        float a = gg * inv;
        op[c] = fmaf(zp[c], a, beta2[col + c] - mean * a);
    }
    ((float4*)out)[i] = o;
}

extern "C" void kernel_launch(void* const* d_in, const int* in_sizes, int n_in,
                              void* d_out, int out_size, void* d_ws, size_t ws_size,
                              hipStream_t stream) {
    const float* features = (const float*)d_in[0];
    const float* edge_w = (const float*)d_in[1];
    const int* src = (const int*)d_in[2];
    const int* dst = (const int*)d_in[3];
    const float* bond_W = (const float*)d_in[4];
    const float* bond_b = (const float*)d_in[5];
    const float* W1 = (const float*)d_in[6];
    const float* b1 = (const float*)d_in[7];
    const float* W2 = (const float*)d_in[8];
    const float* b2 = (const float*)d_in[9];
    const float* gamma1 = (const float*)d_in[10];
    const float* beta1 = (const float*)d_in[11];
    const float* gamma2 = (const float*)d_in[12];
    const float* beta2 = (const float*)d_in[13];
    float* out = (float*)d_out;
    float* ws = (float*)d_ws;

    float* S = ws;                                     // [N,128] -> X1 in place
    float* TD = ws + 6400000;                          // [N,32]
    int* eidx = (int*)(ws + 8000000);                  // [E]
    int* cnt = (int*)(ws + 8800000);                   // [N]
    int* rowptr = (int*)(ws + 8850000);                // [N+1]
    int* wpos = (int*)(ws + 8900016);                  // [N]
    unsigned short* Bt1g = (unsigned short*)(ws + 8950016);  // [128][160]
    unsigned short* Bt2g = (unsigned short*)(ws + 8960256);  // [128][128]
    float* dv = ws + 8968448;                          // [128]
    float* stats = ws + 8968576;                       // s1[256] + s2[256]

    prep0_k<<<196, 256, 0, stream>>>(W1, bond_W, bond_b, b1, cnt, stats, Bt1g);
    hist_k<<<3125, 256, 0, stream>>>(dst, cnt);
    scan_k<<<1, 1024, 0, stream>>>(cnt, rowptr, wpos);
    scat_k<<<3125, 256, 0, stream>>>(dst, wpos, eidx);
    gather_k<<<12500, 256, 0, stream>>>(rowptr, eidx, src, features, edge_w, S, TD);
    // X1 = relu(S@W1 + T@bondW + deg*bondb + b1)  (all folded into K=160 MFMA), stats->s1
    mfma_gemm_k<1, 160><<<782, 256, 0, stream>>>(S, TD, Bt1g, nullptr, nullptr, S, stats, NN);
    fin_k<<<1, 128, 0, stream>>>(stats, gamma1, beta1, W2, b2, Bt2g, dv);
    // Z = relu(X1@W2p + dv + features), stats->s2
    mfma_gemm_k<2, 128><<<782, 256, 0, stream>>>(S, nullptr, Bt2g, features, dv, out,
                                                 stats + 256, NN);
    out_k<<<6250, 256, 0, stream>>>(out, stats + 256, gamma2, beta2, out);
}

// Round 4
// 377.883 us; speedup vs baseline: 2.4902x; 1.2794x over previous
//
#include <hip/hip_runtime.h>

#define NN 50000
#define NE 800000
#define HD 128
#define FBD 16
#define BN_EPS 1e-5f
#define NBLK 196  // ceil(NN/256)

typedef __attribute__((ext_vector_type(8))) short short8;
typedef __attribute__((ext_vector_type(4))) float f32x4;

__device__ __forceinline__ short f2bf(float x) {
    unsigned int u = __float_as_uint(x);
    u += 0x7fff + ((u >> 16) & 1);   // RNE
    return (short)(u >> 16);
}

// ---------------- prep0: zero cnt + stats, build Bt1g = [W1;bondW;bondb;b1;0]^T bf16 ----------------
__global__ __launch_bounds__(256) void prep0_k(const float* __restrict__ W1,
                                               const float* __restrict__ bond_W,
                                               const float* __restrict__ bond_b,
                                               const float* __restrict__ b1,
                                               int* __restrict__ cnt,
                                               float* __restrict__ stats,
                                               unsigned short* __restrict__ Bt1g) {
    int i = blockIdx.x * 256 + threadIdx.x;
    if (i < NN) cnt[i] = 0;
    if (i < 512) stats[i] = 0.f;  // s1[256] + s2[256]
    if (i < 128 * 160) {
        int c = i / 160, k = i % 160;
        float v;
        if (k < 128) v = W1[k * HD + c];
        else if (k < 144) v = bond_W[(k - 128) * HD + c];
        else if (k == 144) v = bond_b[c];
        else if (k == 145) v = b1[c];
        else v = 0.f;
        Bt1g[i] = (unsigned short)f2bf(v);
    }
}

// ---------------- degree histogram ----------------
__global__ __launch_bounds__(256) void hist_k(const int* __restrict__ dst,
                                              int* __restrict__ cnt) {
    int e = blockIdx.x * 256 + threadIdx.x;
    if (e < NE) atomicAdd(&cnt[dst[e]], 1);
}

// ---------------- hierarchical scan: per-block sums ----------------
__global__ __launch_bounds__(256) void psum_k(const int* __restrict__ cnt,
                                              int* __restrict__ bsum) {
    int t = threadIdx.x, b = blockIdx.x;
    int i = b * 256 + t;
    int v = (i < NN) ? cnt[i] : 0;
#pragma unroll
    for (int o = 1; o < 64; o <<= 1) v += __shfl_xor(v, o);
    __shared__ int wsm[4];
    if ((t & 63) == 0) wsm[t >> 6] = v;
    __syncthreads();
    if (t == 0) bsum[b] = wsm[0] + wsm[1] + wsm[2] + wsm[3];
}

// ---------------- scan of block sums (196 entries, 1 block) ----------------
__global__ __launch_bounds__(256) void bscan_k(const int* __restrict__ bsum,
                                               int* __restrict__ boff) {
    __shared__ int sm[256];
    int t = threadIdx.x;
    sm[t] = (t < NBLK) ? bsum[t] : 0;
    __syncthreads();
    for (int o = 1; o < 256; o <<= 1) {
        int v = (t >= o) ? sm[t - o] : 0;
        __syncthreads();
        sm[t] += v;
        __syncthreads();
    }
    if (t < NBLK) boff[t] = (t == 0) ? 0 : sm[t - 1];
}

// ---------------- per-block exclusive scan -> rowptr, wpos ----------------
__global__ __launch_bounds__(256) void rowptr_k(const int* __restrict__ cnt,
                                                const int* __restrict__ boff,
                                                int* __restrict__ rowptr,
                                                int* __restrict__ wpos) {
    __shared__ int sm[256];
    int t = threadIdx.x, b = blockIdx.x;
    int i = b * 256 + t;
    int c = (i < NN) ? cnt[i] : 0;
    sm[t] = c;
    __syncthreads();
    for (int o = 1; o < 256; o <<= 1) {
        int v = (t >= o) ? sm[t - o] : 0;
        __syncthreads();
        sm[t] += v;
        __syncthreads();
    }
    int excl = boff[b] + sm[t] - c;
    if (i < NN) {
        rowptr[i] = excl;
        wpos[i] = excl;
        if (i == NN - 1) rowptr[NN] = excl + c;
    }
}

// ---------------- scatter edge ids into CSR ----------------
__global__ __launch_bounds__(256) void scat_k(const int* __restrict__ dst,
                                              int* __restrict__ wpos,
                                              int* __restrict__ eidx) {
    int e = blockIdx.x * 256 + threadIdx.x;
    if (e < NE) {
        int p = atomicAdd(&wpos[dst[e]], 1);
        eidx[p] = e;
    }
}

// ---------------- gather: S[n] = sum features[src], TD[n] = [sum edge_w | deg | 1 | 0..] ----------------
__global__ __launch_bounds__(256) void gather_k(const int* __restrict__ rowptr,
                                                const int* __restrict__ eidx,
                                                const int* __restrict__ src,
                                                const float* __restrict__ features,
                                                const float* __restrict__ edge_w,
                                                float* __restrict__ S,
                                                float* __restrict__ TD) {
    int wid = blockIdx.x * 4 + (threadIdx.x >> 6);
    if (wid >= NN) return;
    const int lane = threadIdx.x & 63;
    const int half = lane >> 5;   // which row of a pair
    const int q = lane & 31;      // col group (4 cols)
    const int cc = lane & 15;     // edge_w col
    const int g4 = lane >> 4;     // 4 groups for edge_w unroll
    int base = rowptr[wid], end = rowptr[wid + 1];
    float4 acc = {0.f, 0.f, 0.f, 0.f};
    float tacc = 0.f;
    for (int b = base; b < end; b += 64) {
        int n = min(64, end - b);
        int myE = eidx[b + min(lane, n - 1)];
        int myS = src[myE];
        int i = 0;
        for (; i + 4 <= n; i += 4) {
            int sA = __shfl(myS, i + half);       // rows i, i+1
            int sB = __shfl(myS, i + 2 + half);   // rows i+2, i+3
            int eg = __shfl(myE, i + g4);
            float4 fA = *(const float4*)&features[(long)sA * HD + q * 4];
            float4 fB = *(const float4*)&features[(long)sB * HD + q * 4];
            float w = edge_w[(long)eg * FBD + cc];
            acc.x += fA.x + fB.x;
            acc.y += fA.y + fB.y;
            acc.z += fA.z + fB.z;
            acc.w += fA.w + fB.w;
            tacc += w;
        }
        for (; i < n; ++i) {
            int s0 = __shfl(myS, i);
            int e0 = __shfl(myE, i);
            float4 f = *(const float4*)&features[(long)s0 * HD + q * 4];
            if (half == 0) {
                acc.x += f.x; acc.y += f.y; acc.z += f.z; acc.w += f.w;
            }
            if (g4 == 0) tacc += edge_w[(long)e0 * FBD + cc];
        }
    }
    // combine halves (lanes l and l^32 hold partials for same cols)
    acc.x += __shfl_xor(acc.x, 32);
    acc.y += __shfl_xor(acc.y, 32);
    acc.z += __shfl_xor(acc.z, 32);
    acc.w += __shfl_xor(acc.w, 32);
    if (half == 0) *(float4*)&S[(long)wid * HD + q * 4] = acc;
    // edge_w: groups summed disjoint edges
    tacc += __shfl_xor(tacc, 16);
    tacc += __shfl_xor(tacc, 32);
    if (lane < 32) {
        float v = (lane < 16) ? tacc
                              : (lane == 16 ? (float)(end - base) : (lane == 17 ? 1.f : 0.f));
        TD[(long)wid * 32 + lane] = v;
    }
}

// ---------------- bf16 MFMA GEMM: out[M,128] = relu(A[M,KB] @ Bt^T) (+dvec+extra), col stats ----------------
template <int MODE, int KB>
__global__ __launch_bounds__(256) void mfma_gemm_k(const float* __restrict__ A,
                                                   const float* __restrict__ TD,
                                                   const unsigned short* __restrict__ Btg,
                                                   const float* __restrict__ extra,
                                                   const float* __restrict__ dvec,
                                                   float* __restrict__ out,
                                                   float* __restrict__ stats, int M) {
    __shared__ unsigned short Bt[128 * KB];
    __shared__ float redS[4][128];
    __shared__ float redQ[4][128];
    const int tid = threadIdx.x;

    const int nch = 128 * KB * 2 / 16;
    for (int id = tid; id < nch; id += 256) {
        int c = id / (KB / 8);
        int byte = id * 16;
        int sw = byte ^ ((c & 7) << 4);
        *(uint4*)((char*)Bt + sw) = *(const uint4*)((const char*)Btg + byte);
    }
    __syncthreads();

    const int l = tid & 63, wid = tid >> 6;
    const int row0 = blockIdx.x * 64 + wid * 16;
    const int cc = l & 15, g = l >> 4, ko = g * 8;
    const long arow = min(row0 + cc, M - 1);

    f32x4 acc[8] = {};

#pragma unroll
    for (int ks = 0; ks < KB / 32; ++ks) {
        const float* ap;
        if (MODE == 1 && ks == 4)
            ap = TD + arow * 32 + ko;
        else
            ap = A + arow * HD + ks * 32 + ko;
        float4 a0 = *(const float4*)ap;
        float4 a1 = *(const float4*)(ap + 4);
        short8 af;
        af[0] = f2bf(a0.x); af[1] = f2bf(a0.y); af[2] = f2bf(a0.z); af[3] = f2bf(a0.w);
        af[4] = f2bf(a1.x); af[5] = f2bf(a1.y); af[6] = f2bf(a1.z); af[7] = f2bf(a1.w);
#pragma unroll
        for (int cb = 0; cb < 8; ++cb) {
            int byte = (cb * 16 + cc) * (KB * 2) + (ks * 32 + ko) * 2;
            byte ^= (cc & 7) << 4;
            short8 bf = *(const short8*)((const char*)Bt + byte);
            acc[cb] = __builtin_amdgcn_mfma_f32_16x16x32_bf16(af, bf, acc[cb], 0, 0, 0);
        }
    }

#pragma unroll
    for (int cb = 0; cb < 8; ++cb) {
        int col = cb * 16 + cc;
        float dva = (MODE == 2) ? dvec[col] : 0.f;
        float s = 0.f, q = 0.f;
#pragma unroll
        for (int r = 0; r < 4; ++r) {
            int grow = row0 + g * 4 + r;
            if (grow < M) {
                float v = acc[cb][r] + dva;
                if (MODE == 2) v += extra[(long)grow * HD + col];
                v = fmaxf(v, 0.f);
                out[(long)grow * HD + col] = v;
                s += v;
                q += v * v;
            }
        }
        s += __shfl_xor(s, 16);
        s += __shfl_xor(s, 32);
        q += __shfl_xor(q, 16);
        q += __shfl_xor(q, 32);
        if (l < 16) {
            redS[wid][col] = s;
            redQ[wid][col] = q;
        }
    }
    __syncthreads();
    if (tid < 128) {
        float s = redS[0][tid] + redS[1][tid] + redS[2][tid] + redS[3][tid];
        unsafeAtomicAdd(&stats[tid], s);
    } else {
        int c = tid - 128;
        float q = redQ[0][c] + redQ[1][c] + redQ[2][c] + redQ[3][c];
        unsafeAtomicAdd(&stats[128 + c], q);
    }
}

// ---------------- fin: BN1 affine from s1; build Bt2g = (a1 (.) W2)^T bf16 and dv = c1@W2 + b2 ----------------
__global__ __launch_bounds__(128) void fin_k(const float* __restrict__ stats,
                                             const float* __restrict__ gamma1,
                                             const float* __restrict__ beta1,
                                             const float* __restrict__ W2,
                                             const float* __restrict__ b2,
                                             unsigned short* __restrict__ Bt2g,
                                             float* __restrict__ dv) {
    __shared__ float sa[128], sc[128];
    int j = threadIdx.x;
    float mean = stats[j] * (1.f / NN);
    float var = stats[128 + j] * (1.f / NN) - mean * mean;
    float inv = rsqrtf(var + BN_EPS);
    float gg = gamma1[j];
    sa[j] = gg * inv;
    sc[j] = beta1[j] - mean * inv * gg;
    __syncthreads();
    float dj = b2[j];
    for (int k0 = 0; k0 < HD; k0 += 8) {
        short8 v;
#pragma unroll
        for (int u = 0; u < 8; ++u) {
            float w = W2[(k0 + u) * HD + j];
            v[u] = f2bf(sa[k0 + u] * w);
            dj = fmaf(sc[k0 + u], w, dj);
        }
        *(short8*)&Bt2g[(long)j * HD + k0] = v;
    }
    dv[j] = dj;
}

// ---------------- final: out = Z * a2[col] + c2[col] (BN2), float4 ----------------
__global__ __launch_bounds__(256) void out_k(const float* __restrict__ Z,
                                             const float* __restrict__ stats2,
                                             const float* __restrict__ gamma2,
                                             const float* __restrict__ beta2,
                                             float* __restrict__ out) {
    long i = (long)blockIdx.x * 256 + threadIdx.x;
    const long n4 = (long)NN * HD / 4;
    if (i >= n4) return;
    int col = (int)((i & 31) << 2);
    float4 z = ((const float4*)Z)[i];
    float4 o;
    float* zp = (float*)&z;
    float* op = (float*)&o;
#pragma unroll
    for (int c = 0; c < 4; ++c) {
        float mean = stats2[col + c] * (1.f / NN);
        float var = stats2[128 + col + c] * (1.f / NN) - mean * mean;
        float inv = rsqrtf(var + BN_EPS);
        float gg = gamma2[col + c];
        float a = gg * inv;
        op[c] = fmaf(zp[c], a, beta2[col + c] - mean * a);
    }
    ((float4*)out)[i] = o;
}

extern "C" void kernel_launch(void* const* d_in, const int* in_sizes, int n_in,
                              void* d_out, int out_size, void* d_ws, size_t ws_size,
                              hipStream_t stream) {
    const float* features = (const float*)d_in[0];
    const float* edge_w = (const float*)d_in[1];
    const int* src = (const int*)d_in[2];
    const int* dst = (const int*)d_in[3];
    const float* bond_W = (const float*)d_in[4];
    const float* bond_b = (const float*)d_in[5];
    const float* W1 = (const float*)d_in[6];
    const float* b1 = (const float*)d_in[7];
    const float* W2 = (const float*)d_in[8];
    const float* b2 = (const float*)d_in[9];
    const float* gamma1 = (const float*)d_in[10];
    const float* beta1 = (const float*)d_in[11];
    const float* gamma2 = (const float*)d_in[12];
    const float* beta2 = (const float*)d_in[13];
    float* out = (float*)d_out;
    float* ws = (float*)d_ws;

    float* S = ws;                                     // [N,128] -> X1 in place
    float* TD = ws + 6400000;                          // [N,32]
    int* eidx = (int*)(ws + 8000000);                  // [E]
    int* cnt = (int*)(ws + 8800000);                   // [N]
    int* rowptr = (int*)(ws + 8850000);                // [N+1]
    int* wpos = (int*)(ws + 8900016);                  // [N]
    unsigned short* Bt1g = (unsigned short*)(ws + 8950016);  // [128][160]
    unsigned short* Bt2g = (unsigned short*)(ws + 8960256);  // [128][128]
    float* dv = ws + 8968448;                          // [128]
    float* stats = ws + 8968576;                       // s1[256] + s2[256]
    // scan temporaries live in TD's region (TD unused until gather_k)
    int* bsum = (int*)TD;                              // [NBLK]
    int* boff = bsum + 256;                            // [NBLK]

    prep0_k<<<196, 256, 0, stream>>>(W1, bond_W, bond_b, b1, cnt, stats, Bt1g);
    hist_k<<<3125, 256, 0, stream>>>(dst, cnt);
    psum_k<<<NBLK, 256, 0, stream>>>(cnt, bsum);
    bscan_k<<<1, 256, 0, stream>>>(bsum, boff);
    rowptr_k<<<NBLK, 256, 0, stream>>>(cnt, boff, rowptr, wpos);
    scat_k<<<3125, 256, 0, stream>>>(dst, wpos, eidx);
    gather_k<<<12500, 256, 0, stream>>>(rowptr, eidx, src, features, edge_w, S, TD);
    // X1 = relu(S@W1 + T@bondW + deg*bondb + b1)  (K=160 MFMA), stats->s1
    mfma_gemm_k<1, 160><<<782, 256, 0, stream>>>(S, TD, Bt1g, nullptr, nullptr, S, stats, NN);
    fin_k<<<1, 128, 0, stream>>>(stats, gamma1, beta1, W2, b2, Bt2g, dv);
    // Z = relu(X1@W2p + dv + features), stats->s2
    mfma_gemm_k<2, 128><<<782, 256, 0, stream>>>(S, nullptr, Bt2g, features, dv, out,
                                                 stats + 256, NN);
    out_k<<<6250, 256, 0, stream>>>(out, stats + 256, gamma2, beta2, out);
}

// Round 7
// 362.534 us; speedup vs baseline: 2.5956x; 1.0423x over previous
//
#include <hip/hip_runtime.h>

#define NN 50000
#define NE 800000
#define HD 128
#define FBD 16
#define BN_EPS 1e-5f
#define NBLK 196  // ceil(NN/256)

typedef __attribute__((ext_vector_type(8))) short short8;
typedef __attribute__((ext_vector_type(4))) float f32x4;
typedef __attribute__((ext_vector_type(4))) unsigned short ushort4v;
typedef __attribute__((ext_vector_type(8))) unsigned short ushort8v;

__device__ __forceinline__ unsigned short f2bf(float x) {
    unsigned int u = __float_as_uint(x);
    u += 0x7fff + ((u >> 16) & 1);  // RNE
    return (unsigned short)(u >> 16);
}
__device__ __forceinline__ float bf2f(unsigned short h) {
    return __uint_as_float(((unsigned int)h) << 16);
}

// ---------------- prep0: featcvt f32->bf16, zero cnt/stats, build Bt1g ----------------
__global__ __launch_bounds__(256) void prep0_k(const float* __restrict__ features,
                                               const float* __restrict__ W1,
                                               const float* __restrict__ bond_W,
                                               const float* __restrict__ bond_b,
                                               const float* __restrict__ b1,
                                               unsigned short* __restrict__ fb,
                                               int* __restrict__ cnt,
                                               float* __restrict__ stats,
                                               unsigned short* __restrict__ Bt1g) {
    int i = blockIdx.x * 256 + threadIdx.x;  // grid covers 1.6M
    if (i < 1600000) {
        float4 v = ((const float4*)features)[i];
        ushort4v o;
        o[0] = f2bf(v.x); o[1] = f2bf(v.y); o[2] = f2bf(v.z); o[3] = f2bf(v.w);
        ((ushort4v*)fb)[i] = o;
    }
    if (i < NN) cnt[i] = 0;
    if (i < 512) stats[i] = 0.f;
    if (i < 128 * 160) {
        int c = i / 160, k = i % 160;
        float v;
        if (k < 128) v = W1[k * HD + c];
        else if (k < 144) v = bond_W[(k - 128) * HD + c];
        else if (k == 144) v = bond_b[c];
        else if (k == 145) v = b1[c];
        else v = 0.f;
        Bt1g[i] = f2bf(v);
    }
}

// ---------------- degree histogram ----------------
__global__ __launch_bounds__(256) void hist_k(const int* __restrict__ dst,
                                              int* __restrict__ cnt) {
    int e = blockIdx.x * 256 + threadIdx.x;
    if (e < NE) atomicAdd(&cnt[dst[e]], 1);
}

// ---------------- hierarchical scan ----------------
__global__ __launch_bounds__(256) void psum_k(const int* __restrict__ cnt,
                                              int* __restrict__ bsum) {
    int t = threadIdx.x, b = blockIdx.x;
    int i = b * 256 + t;
    int v = (i < NN) ? cnt[i] : 0;
#pragma unroll
    for (int o = 1; o < 64; o <<= 1) v += __shfl_xor(v, o);
    __shared__ int wsm[4];
    if ((t & 63) == 0) wsm[t >> 6] = v;
    __syncthreads();
    if (t == 0) bsum[b] = wsm[0] + wsm[1] + wsm[2] + wsm[3];
}

__global__ __launch_bounds__(256) void bscan_k(const int* __restrict__ bsum,
                                               int* __restrict__ boff) {
    __shared__ int sm[256];
    int t = threadIdx.x;
    sm[t] = (t < NBLK) ? bsum[t] : 0;
    __syncthreads();
    for (int o = 1; o < 256; o <<= 1) {
        int v = (t >= o) ? sm[t - o] : 0;
        __syncthreads();
        sm[t] += v;
        __syncthreads();
    }
    if (t < NBLK) boff[t] = (t == 0) ? 0 : sm[t - 1];
}

__global__ __launch_bounds__(256) void rowptr_k(const int* __restrict__ cnt,
                                                const int* __restrict__ boff,
                                                int* __restrict__ rowptr,
                                                int* __restrict__ wpos) {
    __shared__ int sm[256];
    int t = threadIdx.x, b = blockIdx.x;
    int i = b * 256 + t;
    int c = (i < NN) ? cnt[i] : 0;
    sm[t] = c;
    __syncthreads();
    for (int o = 1; o < 256; o <<= 1) {
        int v = (t >= o) ? sm[t - o] : 0;
        __syncthreads();
        sm[t] += v;
        __syncthreads();
    }
    int excl = boff[b] + sm[t] - c;
    if (i < NN) {
        rowptr[i] = excl;
        wpos[i] = excl;
        if (i == NN - 1) rowptr[NN] = excl + c;
    }
}

// ---------------- scatter {e, src[e]} into CSR ----------------
__global__ __launch_bounds__(256) void scat_k(const int* __restrict__ dst,
                                              const int* __restrict__ src,
                                              int* __restrict__ wpos,
                                              int2* __restrict__ es) {
    int e = blockIdx.x * 256 + threadIdx.x;
    if (e < NE) {
        int p = atomicAdd(&wpos[dst[e]], 1);
        es[p] = make_int2(e, src[e]);
    }
}

// ---------------- gather: Sb[n] = bf16(sum fb[src]), TDb[n] = bf16[sum edge_w | deg | 1 | 0..] ----------------
__global__ __launch_bounds__(256) void gather_k(const int* __restrict__ rowptr,
                                                const int2* __restrict__ es,
                                                const unsigned short* __restrict__ fb,
                                                const float* __restrict__ edge_w,
                                                unsigned short* __restrict__ Sb,
                                                unsigned short* __restrict__ TDb) {
    int wid = blockIdx.x * 4 + (threadIdx.x >> 6);
    if (wid >= NN) return;
    const int lane = threadIdx.x & 63;
    const int g4 = lane >> 4, cc = lane & 15;
    int base = rowptr[wid], end = rowptr[wid + 1];
    float acc[8] = {};
    float tacc = 0.f;
    for (int b = base; b < end; b += 64) {
        int n = min(64, end - b);
        int2 my = es[b + min(lane, n - 1)];
        int i = 0;
        for (; i + 4 <= n; i += 4) {
            int sR = __shfl(my.y, i + g4);  // row for this group's edge
            int eg = __shfl(my.x, i + g4);
            ushort8v f = *(const ushort8v*)&fb[(long)sR * HD + cc * 8];
            float w = edge_w[(long)eg * FBD + cc];
#pragma unroll
            for (int u = 0; u < 8; ++u) acc[u] += bf2f(f[u]);
            tacc += w;
        }
        for (; i < n; ++i) {
            // shfl MUST be executed by all 64 lanes (ds_bpermute from an
            // inactive source lane is undefined) — guard only the accumulate.
            int sR = __shfl(my.y, i);
            int eg = __shfl(my.x, i);
            if (g4 == 0) {
                ushort8v f = *(const ushort8v*)&fb[(long)sR * HD + cc * 8];
#pragma unroll
                for (int u = 0; u < 8; ++u) acc[u] += bf2f(f[u]);
                tacc += edge_w[(long)eg * FBD + cc];
            }
        }
    }
    // combine the 4 lane-groups (same cols, disjoint edges)
#pragma unroll
    for (int u = 0; u < 8; ++u) {
        acc[u] += __shfl_xor(acc[u], 16);
        acc[u] += __shfl_xor(acc[u], 32);
    }
    tacc += __shfl_xor(tacc, 16);
    tacc += __shfl_xor(tacc, 32);
    if (g4 == 0) {  // lanes 0..15
        ushort8v o;
#pragma unroll
        for (int u = 0; u < 8; ++u) o[u] = f2bf(acc[u]);
        *(ushort8v*)&Sb[(long)wid * HD + cc * 8] = o;
    }
    if (lane < 32) {
        float v = (lane < 16) ? tacc
                              : (lane == 16 ? (float)(end - base) : (lane == 17 ? 1.f : 0.f));
        TDb[(long)wid * 32 + lane] = f2bf(v);
    }
}

// ---------------- bf16 MFMA GEMM: relu(A[M,KB]@Bt^T (+dvec+extra)), col stats ----------------
// MODE 1: K=160 (k-step 4 from TDb), writes bf16 out (in-place on A). MODE 2: K=128, +dvec+extra(f32), writes f32 out.
template <int MODE, int KB>
__global__ __launch_bounds__(256) void mfma_gemm_k(const unsigned short* __restrict__ Ab,
                                                   const unsigned short* __restrict__ TDb,
                                                   const unsigned short* __restrict__ Btg,
                                                   const float* __restrict__ extra,
                                                   const float* __restrict__ dvec,
                                                   unsigned short* __restrict__ outb,
                                                   float* __restrict__ outf,
                                                   float* __restrict__ stats, int M) {
    __shared__ unsigned short Bt[128 * KB];
    __shared__ float redS[4][128];
    __shared__ float redQ[4][128];
    const int tid = threadIdx.x;

    const int nch = 128 * KB * 2 / 16;
    for (int id = tid; id < nch; id += 256) {
        int c = id / (KB / 8);
        int byte = id * 16;
        int sw = byte ^ ((c & 7) << 4);
        *(uint4*)((char*)Bt + sw) = *(const uint4*)((const char*)Btg + byte);
    }
    __syncthreads();

    const int l = tid & 63, wid = tid >> 6;
    const int row0 = blockIdx.x * 64 + wid * 16;
    const int cc = l & 15, g = l >> 4, ko = g * 8;
    const long arow = min(row0 + cc, M - 1);

    f32x4 acc[8] = {};

#pragma unroll
    for (int ks = 0; ks < KB / 32; ++ks) {
        const unsigned short* ap;
        if (MODE == 1 && ks == 4)
            ap = TDb + arow * 32 + ko;
        else
            ap = Ab + arow * HD + ks * 32 + ko;
        short8 af = *(const short8*)ap;
#pragma unroll
        for (int cb = 0; cb < 8; ++cb) {
            int byte = (cb * 16 + cc) * (KB * 2) + (ks * 32 + ko) * 2;
            byte ^= (cc & 7) << 4;
            short8 bf = *(const short8*)((const char*)Bt + byte);
            acc[cb] = __builtin_amdgcn_mfma_f32_16x16x32_bf16(af, bf, acc[cb], 0, 0, 0);
        }
    }

#pragma unroll
    for (int cb = 0; cb < 8; ++cb) {
        int col = cb * 16 + cc;
        float dva = (MODE == 2) ? dvec[col] : 0.f;
        float s = 0.f, q = 0.f;
#pragma unroll
        for (int r = 0; r < 4; ++r) {
            int grow = row0 + g * 4 + r;
            if (grow < M) {
                float v = acc[cb][r] + dva;
                if (MODE == 2) v += extra[(long)grow * HD + col];
                v = fmaxf(v, 0.f);
                if (MODE == 1)
                    outb[(long)grow * HD + col] = f2bf(v);
                else
                    outf[(long)grow * HD + col] = v;
                s += v;
                q += v * v;
            }
        }
        s += __shfl_xor(s, 16);
        s += __shfl_xor(s, 32);
        q += __shfl_xor(q, 16);
        q += __shfl_xor(q, 32);
        if (l < 16) {
            redS[wid][col] = s;
            redQ[wid][col] = q;
        }
    }
    __syncthreads();
    if (tid < 128) {
        float s = redS[0][tid] + redS[1][tid] + redS[2][tid] + redS[3][tid];
        unsafeAtomicAdd(&stats[tid], s);
    } else {
        int c = tid - 128;
        float q = redQ[0][c] + redQ[1][c] + redQ[2][c] + redQ[3][c];
        unsafeAtomicAdd(&stats[128 + c], q);
    }
}

// ---------------- fin: BN1 affine; Bt2g = (a1 (.) W2)^T bf16; dv = c1@W2 + b2 ----------------
__global__ __launch_bounds__(128) void fin_k(const float* __restrict__ stats,
                                             const float* __restrict__ gamma1,
                                             const float* __restrict__ beta1,
                                             const float* __restrict__ W2,
                                             const float* __restrict__ b2,
                                             unsigned short* __restrict__ Bt2g,
                                             float* __restrict__ dv) {
    __shared__ float sa[128], sc[128];
    int j = threadIdx.x;
    float mean = stats[j] * (1.f / NN);
    float var = stats[128 + j] * (1.f / NN) - mean * mean;
    float inv = rsqrtf(var + BN_EPS);
    float gg = gamma1[j];
    sa[j] = gg * inv;
    sc[j] = beta1[j] - mean * inv * gg;
    __syncthreads();
    float dj = b2[j];
    for (int k0 = 0; k0 < HD; k0 += 8) {
        ushort8v v;
#pragma unroll
        for (int u = 0; u < 8; ++u) {
            float w = W2[(k0 + u) * HD + j];
            v[u] = f2bf(sa[k0 + u] * w);
            dj = fmaf(sc[k0 + u], w, dj);
        }
        *(ushort8v*)&Bt2g[(long)j * HD + k0] = v;
    }
    dv[j] = dj;
}

// ---------------- final: out = Z * a2[col] + c2[col] (BN2) ----------------
__global__ __launch_bounds__(256) void out_k(const float* __restrict__ Z,
                                             const float* __restrict__ stats2,
                                             const float* __restrict__ gamma2,
                                             const float* __restrict__ beta2,
                                             float* __restrict__ out) {
    long i = (long)blockIdx.x * 256 + threadIdx.x;
    const long n4 = (long)NN * HD / 4;
    if (i >= n4) return;
    int col = (int)((i & 31) << 2);
    float4 z = ((const float4*)Z)[i];
    float4 o;
    float* zp = (float*)&z;
    float* op = (float*)&o;
#pragma unroll
    for (int c = 0; c < 4; ++c) {
        float mean = stats2[col + c] * (1.f / NN);
        float var = stats2[128 + col + c] * (1.f / NN) - mean * mean;
        float inv = rsqrtf(var + BN_EPS);
        float gg = gamma2[col + c];
        float a = gg * inv;
        op[c] = fmaf(zp[c], a, beta2[col + c] - mean * a);
    }
    ((float4*)out)[i] = o;
}

extern "C" void kernel_launch(void* const* d_in, const int* in_sizes, int n_in,
                              void* d_out, int out_size, void* d_ws, size_t ws_size,
                              hipStream_t stream) {
    const float* features = (const float*)d_in[0];
    const float* edge_w = (const float*)d_in[1];
    const int* src = (const int*)d_in[2];
    const int* dst = (const int*)d_in[3];
    const float* bond_W = (const float*)d_in[4];
    const float* bond_b = (const float*)d_in[5];
    const float* W1 = (const float*)d_in[6];
    const float* b1 = (const float*)d_in[7];
    const float* W2 = (const float*)d_in[8];
    const float* b2 = (const float*)d_in[9];
    const float* gamma1 = (const float*)d_in[10];
    const float* beta1 = (const float*)d_in[11];
    const float* gamma2 = (const float*)d_in[12];
    const float* beta2 = (const float*)d_in[13];
    float* out = (float*)d_out;
    float* ws = (float*)d_ws;

    // layout (float-index units)
    unsigned short* Sb = (unsigned short*)ws;              // [N,128] bf16 -> X1 in place
    unsigned short* fb = (unsigned short*)(ws + 3200000);  // [N,128] bf16 features
    unsigned short* TDb = (unsigned short*)(ws + 6400000); // [N,32] bf16
    int2* es = (int2*)(ws + 7200000);                      // [E] {e, src}
    int* cnt = (int*)(ws + 8800000);                       // [N]
    int* rowptr = (int*)(ws + 8850000);                    // [N+1]
    int* wpos = (int*)(ws + 8900004);                      // [N]
    unsigned short* Bt1g = (unsigned short*)(ws + 8950004);  // [128][160]
    unsigned short* Bt2g = (unsigned short*)(ws + 8960244);  // [128][128]
    float* dv = ws + 8968436;                              // [128]
    float* stats = ws + 8968564;                           // s1[256]+s2[256]
    int* bsum = (int*)TDb;                                 // scan temps (pre-gather)
    int* boff = bsum + 256;

    prep0_k<<<6250, 256, 0, stream>>>(features, W1, bond_W, bond_b, b1, fb, cnt, stats, Bt1g);
    hist_k<<<3125, 256, 0, stream>>>(dst, cnt);
    psum_k<<<NBLK, 256, 0, stream>>>(cnt, bsum);
    bscan_k<<<1, 256, 0, stream>>>(bsum, boff);
    rowptr_k<<<NBLK, 256, 0, stream>>>(cnt, boff, rowptr, wpos);
    scat_k<<<3125, 256, 0, stream>>>(dst, src, wpos, es);
    gather_k<<<12500, 256, 0, stream>>>(rowptr, es, fb, edge_w, Sb, TDb);
    // X1 = relu(S@W1 + T@bondW + deg*bondb + b1), K=160 MFMA, stats->s1, bf16 in-place
    mfma_gemm_k<1, 160><<<782, 256, 0, stream>>>(Sb, TDb, Bt1g, nullptr, nullptr, Sb,
                                                 nullptr, stats, NN);
    fin_k<<<1, 128, 0, stream>>>(stats, gamma1, beta1, W2, b2, Bt2g, dv);
    // Z = relu(X1@W2p + dv + features), stats->s2, f32 out
    mfma_gemm_k<2, 128><<<782, 256, 0, stream>>>(Sb, nullptr, Bt2g, features, dv, nullptr,
                                                 out, stats + 256, NN);
    out_k<<<6250, 256, 0, stream>>>(out, stats + 256, gamma2, beta2, out);
}